// Round 8
// baseline (118.063 us; speedup 1.0000x reference)
//
#include <hip/hip_runtime.h>
#include <math.h>

#define Ydim 384
#define Xdim 512
#define NPIX (Ydim * Xdim)
#define EPS 1e-4f
#define PIX_PER_BLOCK 256   // 4 gather tiles x 64 pixels
#define NBLOCKS (NPIX / PIX_PER_BLOCK)   // 768 = 3 blocks/CU exactly

__device__ __forceinline__ float fast_rcp32(float d) {
    float r = __builtin_amdgcn_rcpf(d);
    r = r * (2.f - d * r);
    return r;
}

// Fused quad-fit, restructured so the solve runs at full lane width.
// Gather phase: 512 threads = 64 pixels/tile (8 lanes/pixel, float4
// channels), 4 independent tiles back-to-back (vmcnt-pipelined), costs to
// LDS. One barrier. Solve phase: threads 0..255 (4 full waves) each solve
// one pixel — 32x more solve parallelism than the r3..r7 1-wave-per-block
// tail, which was ~10+ us of near-serial execution per CU.
__global__ __launch_bounds__(512, 4) void qf_fused_kernel(
    const float* __restrict__ feat0,
    const float* __restrict__ feat1,
    const float* __restrict__ flow,
    float* __restrict__ out)    // (NPIX, 6)
{
    __shared__ float cost_lds[PIX_PER_BLOCK * 9];

    const int t   = threadIdx.x;
    const int sub = t & 7;                  // channel quad
    const int gl  = t >> 3;                 // pixel-lane group 0..63
    const int blockPix = blockIdx.x * PIX_PER_BLOCK;

#pragma unroll
    for (int iter = 0; iter < 4; ++iter) {
        const int g   = iter * 64 + gl;     // pixel-in-block 0..255
        const int pix = blockPix + g;
        const int y = pix >> 9;             // X = 512
        const int x = pix & (Xdim - 1);

        const float u = flow[pix * 3 + 0];
        const float v = flow[pix * 3 + 1];
        const float4 f0 = *(const float4*)(feat0 + (size_t)pix * 32 + sub * 4);

        // Reference op order exactly: p = ((x+u)) + (j-1), per-tap floor/clip.
        const float pxc = (float)x + u;
        const float pyc = (float)y + v;

        int   c0[3], c1[3], r0[3], r1[3];
        float wx[3], wy[3];
#pragma unroll
        for (int j = 0; j < 3; ++j) {
            float px = pxc + (float)(j - 1);
            float fx = floorf(px);
            wx[j] = px - fx;
            int xi = min(max((int)fx, 0), Xdim - 1);
            c0[j] = xi;
            c1[j] = min(xi + 1, Xdim - 1);
            float py = pyc + (float)(j - 1);
            float fy = floorf(py);
            wy[j] = py - fy;
            int yi = min(max((int)fy, 0), Ydim - 1);
            r0[j] = yi;
            r1[j] = min(yi + 1, Ydim - 1);
        }

        float cacc[9];
        const bool fast = (c1[0] == c0[1]) & (c1[1] == c0[2])
                        & (r1[0] == r0[1]) & (r1[1] == r0[2]);

        if (fast) {
            // 4x4 unique corner grid: 16 float4 loads via the individually
            // CLIPPED cols/rows (base+idx indexing is OOB-unsafe at borders).
            const int cols[4] = {c0[0], c0[1], c0[2], c1[2]};
            const int rows[4] = {r0[0], r0[1], r0[2], r1[2]};
            float4 F[4][4];
#pragma unroll
            for (int r = 0; r < 4; ++r) {
                const float* rb = feat1 + ((size_t)rows[r] * Xdim) * 32 + sub * 4;
#pragma unroll
                for (int c = 0; c < 4; ++c)
                    F[r][c] = *(const float4*)(rb + (size_t)cols[c] * 32);
            }
#pragma unroll
            for (int i = 0; i < 3; ++i) {
                float wyv = wy[i], omwy = 1.f - wyv;
#pragma unroll
                for (int j = 0; j < 3; ++j) {
                    float wxv = wx[j], omwx = 1.f - wxv;
                    float w00 = omwx * omwy, w01 = wxv * omwy;
                    float w10 = omwx * wyv,  w11 = wxv * wyv;
                    float4 a = F[i][j], bb = F[i][j + 1], c = F[i + 1][j], d = F[i + 1][j + 1];
                    float dx = f0.x - (a.x * w00 + bb.x * w01 + c.x * w10 + d.x * w11);
                    float dy = f0.y - (a.y * w00 + bb.y * w01 + c.y * w10 + d.y * w11);
                    float dz = f0.z - (a.z * w00 + bb.z * w01 + c.z * w10 + d.z * w11);
                    float dw = f0.w - (a.w * w00 + bb.w * w01 + c.w * w10 + d.w * w11);
                    cacc[i * 3 + j] = dx * dx + dy * dy + dz * dz + dw * dw;
                }
            }
        } else {
            // Border pixels: exact per-tap 36-load path.
#pragma unroll
            for (int i = 0; i < 3; ++i) {
                float wyv = wy[i], omwy = 1.f - wyv;
                int rb0 = r0[i] * (Xdim * 32);
                int rb1 = r1[i] * (Xdim * 32);
#pragma unroll
                for (int j = 0; j < 3; ++j) {
                    const float4 f00 = *(const float4*)(feat1 + rb0 + c0[j] * 32 + sub * 4);
                    const float4 f01 = *(const float4*)(feat1 + rb0 + c1[j] * 32 + sub * 4);
                    const float4 f10 = *(const float4*)(feat1 + rb1 + c0[j] * 32 + sub * 4);
                    const float4 f11 = *(const float4*)(feat1 + rb1 + c1[j] * 32 + sub * 4);
                    float wxv = wx[j], omwx = 1.f - wxv;
                    float w00 = omwx * omwy, w01 = wxv * omwy;
                    float w10 = omwx * wyv,  w11 = wxv * wyv;
                    float dx = f0.x - (f00.x * w00 + f01.x * w01 + f10.x * w10 + f11.x * w11);
                    float dy = f0.y - (f00.y * w00 + f01.y * w01 + f10.y * w10 + f11.y * w11);
                    float dz = f0.z - (f00.z * w00 + f01.z * w01 + f10.z * w10 + f11.z * w11);
                    float dw = f0.w - (f00.w * w00 + f01.w * w01 + f10.w * w10 + f11.w * w11);
                    cacc[i * 3 + j] = dx * dx + dy * dy + dz * dz + dw * dw;
                }
            }
        }

        // Reduce over the 8 lanes of the subgroup (xor swizzle, in-register).
#pragma unroll
        for (int m = 1; m <= 4; m <<= 1) {
#pragma unroll
            for (int k = 0; k < 9; ++k)
                cacc[k] += __shfl_xor(cacc[k], m);
        }
        if (sub == 0) {
#pragma unroll
            for (int k = 0; k < 9; ++k)
                cost_lds[g * 9 + k] = cacc[k];   // stride 9: 2-way alias, free
        }
    }
    __syncthreads();

    if (t >= PIX_PER_BLOCK) return;   // threads 0..255 = 4 full waves solve

    float c[9];
#pragma unroll
    for (int k = 0; k < 9; ++k) c[k] = cost_lds[t * 9 + k];

    float cmin = c[0];
#pragma unroll
    for (int k = 1; k < 9; ++k) cmin = fminf(cmin, c[k]);

    float e[9], sumf = 0.f;
#pragma unroll
    for (int k = 0; k < 9; ++k) {
        e[k] = expf(cmin - c[k]);
        sumf += e[k];
    }
    float invs = fast_rcp32(sumf);
    invs = invs * (2.f - sumf * invs);

    float w[9], q[9];
#pragma unroll
    for (int k = 0; k < 9; ++k) {
        w[k] = e[k] * invs;
        q[k] = w[k] * c[k];
    }

    // Moments (design entries in {-1,0,1} => adds only).
    float sc0 = w[0] + w[3] + w[6], sc2 = w[2] + w[5] + w[8];
    float sr0 = w[0] + w[1] + w[2], sr2 = w[6] + w[7] + w[8];
    float S10 = sc2 - sc0, S20 = sc2 + sc0;
    float S01 = sr2 - sr0, S02 = sr2 + sr0;
    float S11 = (w[0] + w[8]) - (w[2] + w[6]);
    float S21 = (w[6] + w[8]) - (w[0] + w[2]);
    float S12 = (w[2] + w[8]) - (w[0] + w[6]);
    float S22 = w[0] + w[2] + w[6] + w[8];
    float S00 = sr0 + w[3] + w[4] + w[5] + sr2;

    float qc0 = q[0] + q[3] + q[6], qc2 = q[2] + q[5] + q[8];
    float qr0 = q[0] + q[1] + q[2], qr2 = q[6] + q[7] + q[8];
    float T10 = qc2 - qc0, T20 = qc2 + qc0;
    float T01 = qr2 - qr0, T02 = qr2 + qr0;
    float T11 = (q[0] + q[8]) - (q[2] + q[6]);
    float T00 = qr0 + q[3] + q[4] + q[5] + qr2;

    // M (symmetric, fp32). Basis [x^2,y^2,xy,x,y,1].
    float M[6][6];
    M[0][0] = S20 + EPS; M[0][1] = S22; M[0][2] = S11; M[0][3] = S10; M[0][4] = S21; M[0][5] = S20;
    M[1][0] = S22; M[1][1] = S02 + EPS; M[1][2] = S11; M[1][3] = S12; M[1][4] = S01; M[1][5] = S02;
    M[2][0] = S11; M[2][1] = S11; M[2][2] = S22 + EPS; M[2][3] = S21; M[2][4] = S12; M[2][5] = S11;
    M[3][0] = S10; M[3][1] = S12; M[3][2] = S21; M[3][3] = S20 + EPS; M[3][4] = S11; M[3][5] = S10;
    M[4][0] = S21; M[4][1] = S01; M[4][2] = S12; M[4][3] = S11; M[4][4] = S02 + EPS; M[4][5] = S01;
    M[5][0] = S20; M[5][1] = S02; M[5][2] = S11; M[5][3] = S10; M[5][4] = S01; M[5][5] = S00 + EPS;
    float rhs[6] = {T20, T02, T11, T10, T01, T00};

    // In-place LU (no pivoting; SPD+eps). Multipliers in strict lower part.
    float ip[6];
#pragma unroll
    for (int p = 0; p < 6; ++p) {
        ip[p] = fast_rcp32(M[p][p]);
#pragma unroll
        for (int r = p + 1; r < 6; ++r) {
            float f = M[r][p] * ip[p];
            M[r][p] = f;
#pragma unroll
            for (int cc = p + 1; cc < 6; ++cc)
                M[r][cc] -= f * M[p][cc];
        }
    }

    float s[6];
#pragma unroll
    for (int p = 0; p < 6; ++p) {
        float tt = rhs[p];
#pragma unroll
        for (int j = 0; j < 6; ++j) if (j < p) tt -= M[p][j] * s[j];
        s[p] = tt;
    }
#pragma unroll
    for (int p = 5; p >= 0; --p) {
        float tt = s[p];
#pragma unroll
        for (int j = 0; j < 6; ++j) if (j > p) tt -= M[p][j] * s[j];
        s[p] = tt * ip[p];
    }

    // One fp64 refinement step (residual from exact fp32 moments).
    double s0 = s[0], s1 = s[1], s2 = s[2], s3 = s[3], s4 = s[4], s5 = s[5];
    double dS20 = S20, dS02 = S02, dS22 = S22, dS11 = S11, dS10 = S10,
           dS01 = S01, dS21 = S21, dS12 = S12, dS00 = S00, dE = (double)EPS;
    double rd[6];
    rd[0] = (double)T20 - ((dS20 + dE) * s0 + dS22 * s1 + dS11 * s2 + dS10 * s3 + dS21 * s4 + dS20 * s5);
    rd[1] = (double)T02 - (dS22 * s0 + (dS02 + dE) * s1 + dS11 * s2 + dS12 * s3 + dS01 * s4 + dS02 * s5);
    rd[2] = (double)T11 - (dS11 * s0 + dS11 * s1 + (dS22 + dE) * s2 + dS21 * s3 + dS12 * s4 + dS11 * s5);
    rd[3] = (double)T10 - (dS10 * s0 + dS12 * s1 + dS21 * s2 + (dS20 + dE) * s3 + dS11 * s4 + dS10 * s5);
    rd[4] = (double)T01 - (dS21 * s0 + dS01 * s1 + dS12 * s2 + dS11 * s3 + (dS02 + dE) * s4 + dS01 * s5);
    rd[5] = (double)T00 - (dS20 * s0 + dS02 * s1 + dS11 * s2 + dS10 * s3 + dS01 * s4 + (dS00 + dE) * s5);

    float d[6];
#pragma unroll
    for (int p = 0; p < 6; ++p) {
        float tt = (float)rd[p];
#pragma unroll
        for (int j = 0; j < 6; ++j) if (j < p) tt -= M[p][j] * d[j];
        d[p] = tt;
    }
#pragma unroll
    for (int p = 5; p >= 0; --p) {
        float tt = d[p];
#pragma unroll
        for (int j = 0; j < 6; ++j) if (j > p) tt -= M[p][j] * d[j];
        d[p] = tt * ip[p];
    }

    const int opix = blockPix + t;
#pragma unroll
    for (int i = 0; i < 6; ++i)
        out[(size_t)opix * 6 + i] = s[i] + d[i];
}

extern "C" void kernel_launch(void* const* d_in, const int* in_sizes, int n_in,
                              void* d_out, int out_size, void* d_ws, size_t ws_size,
                              hipStream_t stream) {
    const float* feat0 = (const float*)d_in[0];
    const float* feat1 = (const float*)d_in[1];
    const float* flow  = (const float*)d_in[2];
    float* out = (float*)d_out;

    qf_fused_kernel<<<dim3(NBLOCKS), dim3(512), 0, stream>>>(feat0, feat1, flow, out);
}